// Round 7
// baseline (340.672 us; speedup 1.0000x reference)
//
#include <hip/hip_runtime.h>
#include <hip/hip_bf16.h>

#define BATCH 2048
#define NCLS 100000
#define NCLS_PAD 100096   // padded to 782 full 128-class tiles
#define DIM 128
#define SCALEF 10.0f
#define LOG2E 1.4426950408889634f
#define NS2 (-SCALEF * LOG2E)   // -10*log2(e)
#define NT 782      // ceil(100000/128) class tiles
#define NCHUNK 196  // chunks of 4 tiles: 196*4 = 784 >= 782

typedef __attribute__((ext_vector_type(8))) short bf16x8;
typedef __attribute__((ext_vector_type(4))) float f32x4;
typedef unsigned short u16;
typedef unsigned int u32;

#if __has_builtin(__builtin_amdgcn_sqrtf)
#define FSQRT __builtin_amdgcn_sqrtf
#else
#define FSQRT sqrtf
#endif
#if __has_builtin(__builtin_amdgcn_exp2f)
#define EXP2 __builtin_amdgcn_exp2f
#else
#define EXP2 exp2f
#endif

static __device__ __forceinline__ float bf2f(u32 u) {
    union { u32 i; float f; } c; c.i = u << 16; return c.f;
}
static __device__ __forceinline__ u16 f2bf(float f) {
    union { float f; u32 i; } c; c.f = f;
    u32 x = c.i;
    x += ((x >> 16) & 1u) + 0x7FFFu;   // round-to-nearest-even
    return (u16)(x >> 16);
}

// ---------------- prep: normalize proxies -> bf16; rows >= NCLS zero-filled ----------------
__global__ void prep_proxies_k(const float* __restrict__ proxies,
                               u16* __restrict__ pbf) {
    int gid = blockIdx.x * 4 + (threadIdx.x >> 6);
    int lane = threadIdx.x & 63;
    if (gid >= NCLS) {   // exact-zero pad rows (tail tile correction relies on this)
        *reinterpret_cast<u32*>(pbf + (size_t)gid * DIM + lane * 2) = 0u;
        return;
    }
    const float2 v = *reinterpret_cast<const float2*>(proxies + (size_t)gid * DIM + lane * 2);
    float ss = v.x * v.x + v.y * v.y;
    #pragma unroll
    for (int off = 1; off < 64; off <<= 1) ss += __shfl_xor(ss, off);
    float rn = rsqrtf(ss);
    u16 b0 = f2bf(v.x * rn), b1 = f2bf(v.y * rn);
    *reinterpret_cast<u32*>(pbf + (size_t)gid * DIM + lane * 2) = (u32)b0 | ((u32)b1 << 16);
}

// ---------------- prep: embeddings -> bf16, esq + analytic LSE shift (log2-scaled) ----------------
__global__ void prep_embed_k(const float* __restrict__ emb,
                             u16* __restrict__ ebf, float* __restrict__ esq,
                             float* __restrict__ nm2a) {
    int gid = blockIdx.x * 4 + (threadIdx.x >> 6);
    int lane = threadIdx.x & 63;
    const float2 v = *reinterpret_cast<const float2*>(emb + (size_t)gid * DIM + lane * 2);
    u16 b0 = f2bf(v.x), b1 = f2bf(v.y);
    *reinterpret_cast<u32*>(ebf + (size_t)gid * DIM + lane * 2) = (u32)b0 | ((u32)b1 << 16);
    float f0 = bf2f(b0), f1 = bf2f(b1);
    float s2 = f0 * f0 + f1 * f1;
    #pragma unroll
    for (int off = 1; off < 64; off <<= 1) s2 += __shfl_xor(s2, off);
    if (lane == 0) {
        esq[gid] = s2;
        // M0 = -10*|sqrt(esq)-1| >= max sim (unit-norm proxies); nm2 = -M0*log2e
        nm2a[gid] = SCALEF * LOG2E * fabsf(sqrtf(s2) - 1.0f);
    }
}

// ---------------- main: per block 128 rows x (4 x 128-class tiles), fused LSE ----------------
__global__ __launch_bounds__(256, 4)
void gemm_lse_k(const u16* __restrict__ pbf, const u16* __restrict__ ebf,
                const float* __restrict__ esq, const float* __restrict__ nm2a,
                float* __restrict__ ps) {
    // B tile: 128 classes x 128 bf16, conflict-free via pre-swizzled global source
    // (global_load_lds writes base+lane*16; reads XOR the chunk index).
    __shared__ __align__(16) u16 lB[128 * DIM];   // 32 KB

    int bid = blockIdx.x;
    int nb = (bid & 7) * 392 + (bid >> 3);   // bijective XCD swizzle, 3136 = 8*392
    int chunk = nb >> 4;                     // 0..195
    int rt = nb & 15;                        // 0..15
    int tid = threadIdx.x;
    int wid = tid >> 6, lane = tid & 63;
    int l15 = lane & 15, lhi = lane >> 4;
    int arowbase = rt * 128 + wid * 32;

    auto stage = [&](int c) {
        int ct128 = (chunk * 4 + c) * 128;
        #pragma unroll
        for (int j = 0; j < 8; ++j) {
            int r = wid * 32 + j * 4 + lhi;
            int kb = l15 ^ (r & 7);                       // pre-swizzled source chunk
            const u16* src = pbf + (size_t)(ct128 + r) * DIM + kb * 8;
            u32 ldsoff = (u32)(wid * 8192 + j * 1024);    // + lane*16 implied by HW
            __builtin_amdgcn_global_load_lds(
                (const __attribute__((address_space(1))) u32*)src,
                (__attribute__((address_space(3))) u32*)((char*)lB + ldsoff),
                16, 0, 0);
        }
    };
    stage(0);

    // A fragments in registers (reused across all 4 class tiles)
    bf16x8 afr[2][4];
    #pragma unroll
    for (int m = 0; m < 2; ++m) {
        const u16* arow = ebf + (size_t)(arowbase + m * 16 + l15) * DIM;
        #pragma unroll
        for (int kk = 0; kk < 4; ++kk)
            afr[m][kk] = *reinterpret_cast<const bf16x8*>(arow + kk * 32 + lhi * 8);
    }
    // per-thread row constants (8 rows each): ep = esq+1 (psq == 1 for unit proxies)
    float ep[2][4], nm2[2][4], accs[2][4];
    #pragma unroll
    for (int m = 0; m < 2; ++m)
        #pragma unroll
        for (int rg = 0; rg < 4; ++rg) {
            int grow = arowbase + m * 16 + lhi * 4 + rg;
            ep[m][rg] = esq[grow] + 1.0f;
            nm2[m][rg] = nm2a[grow];
            accs[m][rg] = 0.0f;
        }

    for (int c = 0; c < 4; ++c) {
        int ct = chunk * 4 + c;
        if (ct >= NT) break;               // block-uniform
        __syncthreads();                   // B[c] staged (vmcnt drain at barrier)

        f32x4 zero = {0.0f, 0.0f, 0.0f, 0.0f};
        f32x4 acc[2][8];
        #pragma unroll
        for (int m = 0; m < 2; ++m)
            #pragma unroll
            for (int n = 0; n < 8; ++n) acc[m][n] = zero;

        #pragma unroll
        for (int kk = 0; kk < 4; ++kk) {
            int kbyte = kk * 64 + lhi * 16;
            #pragma unroll
            for (int n = 0; n < 8; ++n) {
                int cc = n * 16 + l15;
                bf16x8 b = *reinterpret_cast<const bf16x8*>(
                    (const char*)lB + ((cc * 256 + kbyte) ^ ((cc & 7) << 4)));
                acc[0][n] = __builtin_amdgcn_mfma_f32_16x16x32_bf16(afr[0][kk], b, acc[0][n], 0, 0, 0);
                acc[1][n] = __builtin_amdgcn_mfma_f32_16x16x32_bf16(afr[1][kk], b, acc[1][n], 0, 0, 0);
            }
        }
        __syncthreads();                   // all waves done reading B[c]
        if (c < 3 && ct + 1 < NT) stage(c + 1);   // overlap next stage with epilogue

        // epilogue: accs += sum_n exp2(nm2 - 10*log2e*dist); pad cols handled in combine
        #pragma unroll
        for (int m = 0; m < 2; ++m)
            #pragma unroll
            for (int rg = 0; rg < 4; ++rg) {
                float e2 = ep[m][rg], nm = nm2[m][rg];
                float s = accs[m][rg];
                #pragma unroll
                for (int n = 0; n < 8; ++n) {
                    float sq = fmaf(-2.0f, acc[m][n][rg], e2);
                    float d = FSQRT(fmaxf(sq, 0.0f));
                    s += EXP2(fmaf(d, NS2, nm));
                }
                accs[m][rg] = s;
            }
    }

    // one reduction per kernel; ps[chunk][row] -> 512B contiguous per block (no write amp)
    #pragma unroll
    for (int m = 0; m < 2; ++m)
        #pragma unroll
        for (int rg = 0; rg < 4; ++rg) {
            float s = accs[m][rg];
            #pragma unroll
            for (int off = 1; off < 16; off <<= 1) s += __shfl_xor(s, off);
            if (l15 == 0) {
                int grow = arowbase + m * 16 + lhi * 4 + rg;
                ps[(size_t)chunk * BATCH + grow] = s;
            }
        }
}

// ---------------- combine: subtract pad contribution, lse, pos term, weighted loss ----------------
__global__ __launch_bounds__(256)
void combine_k(const float* __restrict__ ps, const u16* __restrict__ ebf,
               const u16* __restrict__ pbf, const float* __restrict__ esq,
               const float* __restrict__ nm2a, const int* __restrict__ labels,
               const float* __restrict__ cw, float* __restrict__ out) {
    int wid = threadIdx.x >> 6, lane = threadIdx.x & 63;
    int row = blockIdx.x * 4 + wid;
    float S = 0.0f;
    for (int t = lane; t < NCHUNK; t += 64) S += ps[(size_t)t * BATCH + row];
    #pragma unroll
    for (int off = 1; off < 64; off <<= 1) S += __shfl_xor(S, off);

    int label = labels[row];
    u32 eu = *reinterpret_cast<const u32*>(ebf + (size_t)row * DIM + lane * 2);
    u32 pu = *reinterpret_cast<const u32*>(pbf + (size_t)label * DIM + lane * 2);
    float d = bf2f(eu & 0xFFFFu) * bf2f(pu & 0xFFFFu)
            + bf2f(eu >> 16)     * bf2f(pu >> 16);
    #pragma unroll
    for (int off = 1; off < 64; off <<= 1) d += __shfl_xor(d, off);

    if (lane == 0) {
        float e2 = esq[row], nm = nm2a[row];
        // exact pad-class correction: 96 zero-rows contributed exp2(fmaf(sqrt(e2+1),NS2,nm)) each
        // (bitwise-same ops as the gemm epilogue: fmaf(-2,0,ep)==ep, same FSQRT/fmaf/EXP2)
        float dp = FSQRT(fmaxf(fmaf(-2.0f, 0.0f, e2 + 1.0f), 0.0f));
        float corr = 96.0f * EXP2(fmaf(dp, NS2, nm));
        float lse = -nm * (1.0f / LOG2E) + logf(S - corr);
        float sq = e2 + 1.0f - 2.0f * d;
        float pos = -SCALEF * FSQRT(fmaxf(sq, 0.0f));
        atomicAdd(out, (lse - pos) * cw[label] * (1.0f / BATCH));
    }
}

extern "C" void kernel_launch(void* const* d_in, const int* in_sizes, int n_in,
                              void* d_out, int out_size, void* d_ws, size_t ws_size,
                              hipStream_t stream) {
    const float* emb     = (const float*)d_in[0];
    const int*   labels  = (const int*)d_in[1];
    const float* cw      = (const float*)d_in[2];
    const float* proxies = (const float*)d_in[3];
    float* out = (float*)d_out;

    char* ws = (char*)d_ws;
    // layout (bytes):
    // pbf:  0          .. 25,624,576   (100096*128 bf16, incl. 96 zero pad rows)
    // ebf:  25,624,576 .. 26,148,864   (2048*128 bf16)
    // esq:  26,148,864 .. 26,157,056   (2048 f32)
    // nm2:  26,157,056 .. 26,165,248   (2048 f32)
    // ps:   26,165,248 .. 27,770,880   (196*2048 f32, [chunk][row])
    u16*   pbf  = (u16*)ws;
    u16*   ebf  = (u16*)(ws + 25624576);
    float* esq  = (float*)(ws + 26148864);
    float* nm2  = (float*)(ws + 26157056);
    float* ps   = (float*)(ws + 26165248);

    hipMemsetAsync(d_out, 0, sizeof(float), stream);
    prep_proxies_k<<<25024, 256, 0, stream>>>(proxies, pbf);
    prep_embed_k<<<512, 256, 0, stream>>>(emb, ebf, esq, nm2);
    gemm_lse_k<<<3136, 256, 0, stream>>>(pbf, ebf, esq, nm2, ps);
    combine_k<<<512, 256, 0, stream>>>(ps, ebf, pbf, esq, nm2, labels, cw, out);
}

// Round 8
// 303.712 us; speedup vs baseline: 1.1217x; 1.1217x over previous
//
#include <hip/hip_runtime.h>
#include <hip/hip_bf16.h>

#define BATCH 2048
#define NCLS 100000
#define NCLS_PAD 100096   // padded to 782 full 128-class tiles
#define DIM 128
#define SCALEF 10.0f
#define LOG2E 1.4426950408889634f
#define NS2 (-SCALEF * LOG2E)   // -10*log2(e)
#define NT 782      // ceil(100000/128) class tiles
#define NCHUNK 196  // chunks of 4 tiles: 196*4 = 784 >= 782

typedef __attribute__((ext_vector_type(8))) short bf16x8;
typedef __attribute__((ext_vector_type(4))) float f32x4;
typedef unsigned short u16;
typedef unsigned int u32;

#if __has_builtin(__builtin_amdgcn_sqrtf)
#define FSQRT __builtin_amdgcn_sqrtf
#else
#define FSQRT sqrtf
#endif
#if __has_builtin(__builtin_amdgcn_exp2f)
#define EXP2 __builtin_amdgcn_exp2f
#else
#define EXP2 exp2f
#endif

static __device__ __forceinline__ float bf2f(u32 u) {
    union { u32 i; float f; } c; c.i = u << 16; return c.f;
}
static __device__ __forceinline__ u16 f2bf(float f) {
    union { float f; u32 i; } c; c.f = f;
    u32 x = c.i;
    x += ((x >> 16) & 1u) + 0x7FFFu;   // round-to-nearest-even
    return (u16)(x >> 16);
}

// ---------------- prep: normalize proxies -> bf16; 4 lanes per row, 2 shfl ----------------
__global__ __launch_bounds__(256)
void prep_proxies_k(const float* __restrict__ proxies, u16* __restrict__ pbf) {
    int gid = blockIdx.x * 256 + threadIdx.x;   // 400384 tasks = 100096 rows * 4
    int r = gid >> 2, q = gid & 3;
    u16* dst = pbf + (size_t)r * DIM + q * 32;
    if (r >= NCLS) {   // exact-zero pad rows (tail correction relies on this)
        #pragma unroll
        for (int j = 0; j < 4; ++j)
            *reinterpret_cast<uint4*>(dst + j * 8) = uint4{0, 0, 0, 0};
        return;
    }
    const float* src = proxies + (size_t)r * DIM + q * 32;
    float v[32];
    float ss = 0.0f;
    #pragma unroll
    for (int j = 0; j < 8; ++j) {
        float4 t = *reinterpret_cast<const float4*>(src + j * 4);
        v[j*4+0] = t.x; v[j*4+1] = t.y; v[j*4+2] = t.z; v[j*4+3] = t.w;
        ss += t.x*t.x + t.y*t.y + t.z*t.z + t.w*t.w;
    }
    ss += __shfl_xor(ss, 1);   // quad (lanes q=0..3 of same row) reduce
    ss += __shfl_xor(ss, 2);
    float rn = rsqrtf(ss);
    #pragma unroll
    for (int j = 0; j < 4; ++j) {
        uint4 o;
        o.x = (u32)f2bf(v[j*8+0]*rn) | ((u32)f2bf(v[j*8+1]*rn) << 16);
        o.y = (u32)f2bf(v[j*8+2]*rn) | ((u32)f2bf(v[j*8+3]*rn) << 16);
        o.z = (u32)f2bf(v[j*8+4]*rn) | ((u32)f2bf(v[j*8+5]*rn) << 16);
        o.w = (u32)f2bf(v[j*8+6]*rn) | ((u32)f2bf(v[j*8+7]*rn) << 16);
        *reinterpret_cast<uint4*>(dst + j * 8) = o;
    }
}

// ---------------- prep: embeddings -> bf16, esq + analytic LSE shift (log2-scaled) ----------------
__global__ void prep_embed_k(const float* __restrict__ emb,
                             u16* __restrict__ ebf, float* __restrict__ esq,
                             float* __restrict__ nm2a) {
    int gid = blockIdx.x * 4 + (threadIdx.x >> 6);
    int lane = threadIdx.x & 63;
    const float2 v = *reinterpret_cast<const float2*>(emb + (size_t)gid * DIM + lane * 2);
    u16 b0 = f2bf(v.x), b1 = f2bf(v.y);
    *reinterpret_cast<u32*>(ebf + (size_t)gid * DIM + lane * 2) = (u32)b0 | ((u32)b1 << 16);
    float f0 = bf2f(b0), f1 = bf2f(b1);
    float s2 = f0 * f0 + f1 * f1;
    #pragma unroll
    for (int off = 1; off < 64; off <<= 1) s2 += __shfl_xor(s2, off);
    if (lane == 0) {
        esq[gid] = s2;
        // M0 = -10*|sqrt(esq)-1| >= max sim (unit-norm proxies); nm2 = -M0*log2e
        nm2a[gid] = SCALEF * LOG2E * fabsf(sqrtf(s2) - 1.0f);
    }
}

// ---------------- main: per block 128 rows x (4 x 128-class tiles), fused LSE ----------------
__global__ __launch_bounds__(256, 4)
void gemm_lse_k(const u16* __restrict__ pbf, const u16* __restrict__ ebf,
                const float* __restrict__ esq, const float* __restrict__ nm2a,
                float* __restrict__ ps) {
    // B tile: 128 classes x 128 bf16, conflict-free via pre-swizzled global source
    // (global_load_lds writes base+lane*16; reads XOR the chunk index).
    __shared__ __align__(16) u16 lB[128 * DIM];   // 32 KB

    int bid = blockIdx.x;
    int nb = (bid & 7) * 392 + (bid >> 3);   // bijective XCD swizzle, 3136 = 8*392
    int chunk = nb >> 4;                     // 0..195
    int rt = nb & 15;                        // 0..15
    int tid = threadIdx.x;
    int wid = tid >> 6, lane = tid & 63;
    int l15 = lane & 15, lhi = lane >> 4;
    int arowbase = rt * 128 + wid * 32;

    auto stage = [&](int c) {
        int ct128 = (chunk * 4 + c) * 128;
        #pragma unroll
        for (int j = 0; j < 8; ++j) {
            int r = wid * 32 + j * 4 + lhi;
            int kb = l15 ^ (r & 7);                       // pre-swizzled source chunk
            const u16* src = pbf + (size_t)(ct128 + r) * DIM + kb * 8;
            u32 ldsoff = (u32)(wid * 8192 + j * 1024);    // + lane*16 implied by HW
            __builtin_amdgcn_global_load_lds(
                (const __attribute__((address_space(1))) u32*)src,
                (__attribute__((address_space(3))) u32*)((char*)lB + ldsoff),
                16, 0, 0);
        }
    };
    stage(0);

    // A fragments in registers (reused across all 4 class tiles)
    bf16x8 afr[2][4];
    #pragma unroll
    for (int m = 0; m < 2; ++m) {
        const u16* arow = ebf + (size_t)(arowbase + m * 16 + l15) * DIM;
        #pragma unroll
        for (int kk = 0; kk < 4; ++kk)
            afr[m][kk] = *reinterpret_cast<const bf16x8*>(arow + kk * 32 + lhi * 8);
    }
    // per-thread row constants (8 rows each): ep = esq+1 (psq == 1 for unit proxies)
    float ep[2][4], nm2[2][4], accs[2][4];
    #pragma unroll
    for (int m = 0; m < 2; ++m)
        #pragma unroll
        for (int rg = 0; rg < 4; ++rg) {
            int grow = arowbase + m * 16 + lhi * 4 + rg;
            ep[m][rg] = esq[grow] + 1.0f;
            nm2[m][rg] = nm2a[grow];
            accs[m][rg] = 0.0f;
        }

    // epilogue for a 4-column group; acc passed by reference, n-group base gbase in {0,4}
    auto epi = [&](f32x4 (&acc)[2][4]) {
        #pragma unroll
        for (int m = 0; m < 2; ++m)
            #pragma unroll
            for (int rg = 0; rg < 4; ++rg) {
                float e2 = ep[m][rg], nm = nm2[m][rg];
                float s = accs[m][rg];
                #pragma unroll
                for (int n = 0; n < 4; ++n) {
                    float sq = fmaf(-2.0f, acc[m][n][rg], e2);   // >= (|e|-1)^2 > 0
                    float d = FSQRT(sq);
                    s += EXP2(fmaf(d, NS2, nm));
                }
                accs[m][rg] = s;
            }
    };

    for (int c = 0; c < 4; ++c) {
        int ct = chunk * 4 + c;
        if (ct >= NT) break;               // block-uniform
        __syncthreads();                   // B[c] staged (vmcnt drain at barrier)

        f32x4 zero = {0.0f, 0.0f, 0.0f, 0.0f};
        f32x4 accA[2][4], accB[2][4];
        #pragma unroll
        for (int m = 0; m < 2; ++m)
            #pragma unroll
            for (int n = 0; n < 4; ++n) { accA[m][n] = zero; accB[m][n] = zero; }

        // group 0: n-tiles 0..3
        #pragma unroll
        for (int kk = 0; kk < 4; ++kk) {
            int kbyte = kk * 64 + lhi * 16;
            #pragma unroll
            for (int n = 0; n < 4; ++n) {
                int cc = n * 16 + l15;
                bf16x8 b = *reinterpret_cast<const bf16x8*>(
                    (const char*)lB + ((cc * 256 + kbyte) ^ ((cc & 7) << 4)));
                accA[0][n] = __builtin_amdgcn_mfma_f32_16x16x32_bf16(afr[0][kk], b, accA[0][n], 0, 0, 0);
                accA[1][n] = __builtin_amdgcn_mfma_f32_16x16x32_bf16(afr[1][kk], b, accA[1][n], 0, 0, 0);
            }
        }
        epi(accA);   // overlaps with group-1 MFMA issue (separate pipes)

        // group 1: n-tiles 4..7
        #pragma unroll
        for (int kk = 0; kk < 4; ++kk) {
            int kbyte = kk * 64 + lhi * 16;
            #pragma unroll
            for (int n = 0; n < 4; ++n) {
                int cc = (4 + n) * 16 + l15;
                bf16x8 b = *reinterpret_cast<const bf16x8*>(
                    (const char*)lB + ((cc * 256 + kbyte) ^ ((cc & 7) << 4)));
                accB[0][n] = __builtin_amdgcn_mfma_f32_16x16x32_bf16(afr[0][kk], b, accB[0][n], 0, 0, 0);
                accB[1][n] = __builtin_amdgcn_mfma_f32_16x16x32_bf16(afr[1][kk], b, accB[1][n], 0, 0, 0);
            }
        }
        __syncthreads();                   // all waves done reading B[c]
        if (c < 3 && ct + 1 < NT) stage(c + 1);   // staging overlaps group-1 epilogue
        epi(accB);
    }

    // one reduction per kernel; ps[chunk][row] -> 512B contiguous per block (no write amp)
    #pragma unroll
    for (int m = 0; m < 2; ++m)
        #pragma unroll
        for (int rg = 0; rg < 4; ++rg) {
            float s = accs[m][rg];
            #pragma unroll
            for (int off = 1; off < 16; off <<= 1) s += __shfl_xor(s, off);
            if (l15 == 0) {
                int grow = arowbase + m * 16 + lhi * 4 + rg;
                ps[(size_t)chunk * BATCH + grow] = s;
            }
        }
}

// ---------------- combine: subtract pad contribution, lse, pos term, weighted loss ----------------
__global__ __launch_bounds__(256)
void combine_k(const float* __restrict__ ps, const u16* __restrict__ ebf,
               const u16* __restrict__ pbf, const float* __restrict__ esq,
               const float* __restrict__ nm2a, const int* __restrict__ labels,
               const float* __restrict__ cw, float* __restrict__ out) {
    int wid = threadIdx.x >> 6, lane = threadIdx.x & 63;
    int row = blockIdx.x * 4 + wid;
    float S = 0.0f;
    for (int t = lane; t < NCHUNK; t += 64) S += ps[(size_t)t * BATCH + row];
    #pragma unroll
    for (int off = 1; off < 64; off <<= 1) S += __shfl_xor(S, off);

    int label = labels[row];
    u32 eu = *reinterpret_cast<const u32*>(ebf + (size_t)row * DIM + lane * 2);
    u32 pu = *reinterpret_cast<const u32*>(pbf + (size_t)label * DIM + lane * 2);
    float d = bf2f(eu & 0xFFFFu) * bf2f(pu & 0xFFFFu)
            + bf2f(eu >> 16)     * bf2f(pu >> 16);
    #pragma unroll
    for (int off = 1; off < 64; off <<= 1) d += __shfl_xor(d, off);

    if (lane == 0) {
        float e2 = esq[row], nm = nm2a[row];
        // exact pad-class correction: 96 zero-rows contributed exp2(fmaf(sqrt(e2+1),NS2,nm))
        // each (bitwise-same ops as gemm epilogue: fmaf(-2,0,ep)==ep, same FSQRT/fmaf/EXP2)
        float dp = FSQRT(e2 + 1.0f);
        float corr = 96.0f * EXP2(fmaf(dp, NS2, nm));
        float lse = -nm * (1.0f / LOG2E) + logf(S - corr);
        float sq = e2 + 1.0f - 2.0f * d;
        float pos = -SCALEF * FSQRT(fmaxf(sq, 0.0f));
        atomicAdd(out, (lse - pos) * cw[label] * (1.0f / BATCH));
    }
}

extern "C" void kernel_launch(void* const* d_in, const int* in_sizes, int n_in,
                              void* d_out, int out_size, void* d_ws, size_t ws_size,
                              hipStream_t stream) {
    const float* emb     = (const float*)d_in[0];
    const int*   labels  = (const int*)d_in[1];
    const float* cw      = (const float*)d_in[2];
    const float* proxies = (const float*)d_in[3];
    float* out = (float*)d_out;

    char* ws = (char*)d_ws;
    // layout (bytes):
    // pbf:  0          .. 25,624,576   (100096*128 bf16, incl. 96 zero pad rows)
    // ebf:  25,624,576 .. 26,148,864   (2048*128 bf16)
    // esq:  26,148,864 .. 26,157,056   (2048 f32)
    // nm2:  26,157,056 .. 26,165,248   (2048 f32)
    // ps:   26,165,248 .. 27,770,880   (196*2048 f32, [chunk][row])
    u16*   pbf  = (u16*)ws;
    u16*   ebf  = (u16*)(ws + 25624576);
    float* esq  = (float*)(ws + 26148864);
    float* nm2  = (float*)(ws + 26157056);
    float* ps   = (float*)(ws + 26165248);

    hipMemsetAsync(d_out, 0, sizeof(float), stream);
    prep_proxies_k<<<1564, 256, 0, stream>>>(proxies, pbf);
    prep_embed_k<<<512, 256, 0, stream>>>(emb, ebf, esq, nm2);
    gemm_lse_k<<<3136, 256, 0, stream>>>(pbf, ebf, esq, nm2, ps);
    combine_k<<<512, 256, 0, stream>>>(ps, ebf, pbf, esq, nm2, labels, cw, out);
}

// Round 13
// 210.179 us; speedup vs baseline: 1.6209x; 1.4450x over previous
//
#include <hip/hip_runtime.h>
#include <hip/hip_bf16.h>

#define BATCH 2048
#define NCLS 100000
#define NCLS_PAD 100096   // padded to 782 full 128-class tiles
#define DIM 128
#define SCALEF 10.0f
#define LOG2E 1.4426950408889634f
#define NS2 (-SCALEF * LOG2E)   // -10*log2(e)
#define NT 782      // ceil(100000/128) class tiles
#define NCHUNK 196  // chunks of 4 tiles: 196*4 = 784 >= 782

typedef __attribute__((ext_vector_type(8))) short bf16x8;
typedef __attribute__((ext_vector_type(4))) float f32x4;
typedef unsigned short u16;
typedef unsigned int u32;

#if __has_builtin(__builtin_amdgcn_sqrtf)
#define FSQRT __builtin_amdgcn_sqrtf
#else
#define FSQRT sqrtf
#endif
#if __has_builtin(__builtin_amdgcn_exp2f)
#define EXP2 __builtin_amdgcn_exp2f
#else
#define EXP2 exp2f
#endif

static __device__ __forceinline__ float bf2f(u32 u) {
    union { u32 i; float f; } c; c.i = u << 16; return c.f;
}
static __device__ __forceinline__ u16 f2bf(float f) {
    union { float f; u32 i; } c; c.f = f;
    u32 x = c.i;
    x += ((x >> 16) & 1u) + 0x7FFFu;   // round-to-nearest-even
    return (u16)(x >> 16);
}

// ---------------- prep: normalize proxies -> bf16; 4 lanes per row, 2 shfl ----------------
__global__ __launch_bounds__(256)
void prep_proxies_k(const float* __restrict__ proxies, u16* __restrict__ pbf) {
    int gid = blockIdx.x * 256 + threadIdx.x;   // 400384 tasks = 100096 rows * 4
    int r = gid >> 2, q = gid & 3;
    u16* dst = pbf + (size_t)r * DIM + q * 32;
    if (r >= NCLS) {   // exact-zero pad rows (tail correction relies on this)
        #pragma unroll
        for (int j = 0; j < 4; ++j)
            *reinterpret_cast<uint4*>(dst + j * 8) = uint4{0, 0, 0, 0};
        return;
    }
    const float* src = proxies + (size_t)r * DIM + q * 32;
    float v[32];
    float ss = 0.0f;
    #pragma unroll
    for (int j = 0; j < 8; ++j) {
        float4 t = *reinterpret_cast<const float4*>(src + j * 4);
        v[j*4+0] = t.x; v[j*4+1] = t.y; v[j*4+2] = t.z; v[j*4+3] = t.w;
        ss += t.x*t.x + t.y*t.y + t.z*t.z + t.w*t.w;
    }
    ss += __shfl_xor(ss, 1);   // quad (lanes q=0..3 of same row) reduce
    ss += __shfl_xor(ss, 2);
    float rn = rsqrtf(ss);
    #pragma unroll
    for (int j = 0; j < 4; ++j) {
        uint4 o;
        o.x = (u32)f2bf(v[j*8+0]*rn) | ((u32)f2bf(v[j*8+1]*rn) << 16);
        o.y = (u32)f2bf(v[j*8+2]*rn) | ((u32)f2bf(v[j*8+3]*rn) << 16);
        o.z = (u32)f2bf(v[j*8+4]*rn) | ((u32)f2bf(v[j*8+5]*rn) << 16);
        o.w = (u32)f2bf(v[j*8+6]*rn) | ((u32)f2bf(v[j*8+7]*rn) << 16);
        *reinterpret_cast<uint4*>(dst + j * 8) = o;
    }
}

// ---------------- prep: embeddings -> bf16, esq + analytic LSE shift (log2-scaled) ----------------
__global__ void prep_embed_k(const float* __restrict__ emb,
                             u16* __restrict__ ebf, float* __restrict__ esq,
                             float* __restrict__ nm2a) {
    int gid = blockIdx.x * 4 + (threadIdx.x >> 6);
    int lane = threadIdx.x & 63;
    const float2 v = *reinterpret_cast<const float2*>(emb + (size_t)gid * DIM + lane * 2);
    u16 b0 = f2bf(v.x), b1 = f2bf(v.y);
    *reinterpret_cast<u32*>(ebf + (size_t)gid * DIM + lane * 2) = (u32)b0 | ((u32)b1 << 16);
    float f0 = bf2f(b0), f1 = bf2f(b1);
    float s2 = f0 * f0 + f1 * f1;
    #pragma unroll
    for (int off = 1; off < 64; off <<= 1) s2 += __shfl_xor(s2, off);
    if (lane == 0) {
        esq[gid] = s2;
        // M0 = -10*|sqrt(esq)-1| >= max sim (unit-norm proxies); nm2 = -M0*log2e
        nm2a[gid] = SCALEF * LOG2E * fabsf(sqrtf(s2) - 1.0f);
    }
}

// ---------------- main: per block 128 rows x (4 x 128-class tiles), fused LSE ----------------
__global__ __launch_bounds__(256, 3)
void gemm_lse_k(const u16* __restrict__ pbf, const u16* __restrict__ ebf,
                const float* __restrict__ esq, const float* __restrict__ nm2a,
                float* __restrict__ ps) {
    // B tile: 128 classes x 128 bf16, conflict-free via pre-swizzled global source
    // (global_load_lds writes base+lane*16; reads XOR the chunk index).
    __shared__ __align__(16) u16 lB[128 * DIM];   // 32 KB

    int bid = blockIdx.x;
    int nb = (bid & 7) * 392 + (bid >> 3);   // bijective XCD swizzle, 3136 = 8*392
    int chunk = nb >> 4;                     // 0..195
    int rt = nb & 15;                        // 0..15
    int tid = threadIdx.x;
    int wid = tid >> 6, lane = tid & 63;
    int l15 = lane & 15, lhi = lane >> 4;
    int arowbase = rt * 128 + wid * 32;

    auto stage = [&](int c) {
        int ct128 = (chunk * 4 + c) * 128;
        #pragma unroll
        for (int j = 0; j < 8; ++j) {
            int r = wid * 32 + j * 4 + lhi;
            int kb = l15 ^ (r & 7);                       // pre-swizzled source chunk
            const u16* src = pbf + (size_t)(ct128 + r) * DIM + kb * 8;
            u32 ldsoff = (u32)(wid * 8192 + j * 1024);    // + lane*16 implied by HW
            __builtin_amdgcn_global_load_lds(
                (const __attribute__((address_space(1))) u32*)src,
                (__attribute__((address_space(3))) u32*)((char*)lB + ldsoff),
                16, 0, 0);
        }
    };
    stage(0);

    // A fragments in registers (reused across all 4 class tiles)
    bf16x8 afr[2][4];
    #pragma unroll
    for (int m = 0; m < 2; ++m) {
        const u16* arow = ebf + (size_t)(arowbase + m * 16 + l15) * DIM;
        #pragma unroll
        for (int kk = 0; kk < 4; ++kk)
            afr[m][kk] = *reinterpret_cast<const bf16x8*>(arow + kk * 32 + lhi * 8);
    }
    // per-thread row constants (8 rows each): ep = esq+1 (psq == 1 for unit proxies)
    float ep[2][4], nm2[2][4], accs[2][4];
    #pragma unroll
    for (int m = 0; m < 2; ++m)
        #pragma unroll
        for (int rg = 0; rg < 4; ++rg) {
            int grow = arowbase + m * 16 + lhi * 4 + rg;
            ep[m][rg] = esq[grow] + 1.0f;
            nm2[m][rg] = nm2a[grow];
            accs[m][rg] = 0.0f;
        }

    // single acc group, reused sequentially (keeps peak live regs < cap: no spill)
    f32x4 acc[2][4];
    auto epi = [&]() {
        #pragma unroll
        for (int m = 0; m < 2; ++m)
            #pragma unroll
            for (int rg = 0; rg < 4; ++rg) {
                float e2 = ep[m][rg], nm = nm2[m][rg];
                float s = accs[m][rg];
                #pragma unroll
                for (int n = 0; n < 4; ++n) {
                    float sq = fmaf(-2.0f, acc[m][n][rg], e2);   // >= (|e|-1)^2 > 0
                    float d = FSQRT(sq);
                    s += EXP2(fmaf(d, NS2, nm));
                }
                accs[m][rg] = s;
            }
    };

    for (int c = 0; c < 4; ++c) {
        int ct = chunk * 4 + c;
        if (ct >= NT) break;               // block-uniform
        __syncthreads();                   // B[c] staged (vmcnt drain at barrier)

        f32x4 zero = {0.0f, 0.0f, 0.0f, 0.0f};
        // group 0: n-tiles 0..3
        #pragma unroll
        for (int m = 0; m < 2; ++m)
            #pragma unroll
            for (int n = 0; n < 4; ++n) acc[m][n] = zero;
        #pragma unroll
        for (int kk = 0; kk < 4; ++kk) {
            int kbyte = kk * 64 + lhi * 16;
            #pragma unroll
            for (int n = 0; n < 4; ++n) {
                int cc = n * 16 + l15;
                bf16x8 b = *reinterpret_cast<const bf16x8*>(
                    (const char*)lB + ((cc * 256 + kbyte) ^ ((cc & 7) << 4)));
                acc[0][n] = __builtin_amdgcn_mfma_f32_16x16x32_bf16(afr[0][kk], b, acc[0][n], 0, 0, 0);
                acc[1][n] = __builtin_amdgcn_mfma_f32_16x16x32_bf16(afr[1][kk], b, acc[1][n], 0, 0, 0);
            }
        }
        epi();   // acc dead after this; regs reused for group 1

        // group 1: n-tiles 4..7
        #pragma unroll
        for (int m = 0; m < 2; ++m)
            #pragma unroll
            for (int n = 0; n < 4; ++n) acc[m][n] = zero;
        #pragma unroll
        for (int kk = 0; kk < 4; ++kk) {
            int kbyte = kk * 64 + lhi * 16;
            #pragma unroll
            for (int n = 0; n < 4; ++n) {
                int cc = (4 + n) * 16 + l15;
                bf16x8 b = *reinterpret_cast<const bf16x8*>(
                    (const char*)lB + ((cc * 256 + kbyte) ^ ((cc & 7) << 4)));
                acc[0][n] = __builtin_amdgcn_mfma_f32_16x16x32_bf16(afr[0][kk], b, acc[0][n], 0, 0, 0);
                acc[1][n] = __builtin_amdgcn_mfma_f32_16x16x32_bf16(afr[1][kk], b, acc[1][n], 0, 0, 0);
            }
        }
        __syncthreads();                   // all waves done reading B[c]
        if (c < 3 && ct + 1 < NT) stage(c + 1);   // staging overlaps group-1 epilogue
        epi();
    }

    // one reduction per kernel; ps[chunk][row] -> 512B contiguous per block (no write amp)
    #pragma unroll
    for (int m = 0; m < 2; ++m)
        #pragma unroll
        for (int rg = 0; rg < 4; ++rg) {
            float s = accs[m][rg];
            #pragma unroll
            for (int off = 1; off < 16; off <<= 1) s += __shfl_xor(s, off);
            if (l15 == 0) {
                int grow = arowbase + m * 16 + lhi * 4 + rg;
                ps[(size_t)chunk * BATCH + grow] = s;
            }
        }
}

// ---------------- combine: subtract pad contribution, lse, pos term, weighted loss ----------------
__global__ __launch_bounds__(256)
void combine_k(const float* __restrict__ ps, const u16* __restrict__ ebf,
               const u16* __restrict__ pbf, const float* __restrict__ esq,
               const float* __restrict__ nm2a, const int* __restrict__ labels,
               const float* __restrict__ cw, float* __restrict__ out) {
    int wid = threadIdx.x >> 6, lane = threadIdx.x & 63;
    int row = blockIdx.x * 4 + wid;
    float S = 0.0f;
    for (int t = lane; t < NCHUNK; t += 64) S += ps[(size_t)t * BATCH + row];
    #pragma unroll
    for (int off = 1; off < 64; off <<= 1) S += __shfl_xor(S, off);

    int label = labels[row];
    u32 eu = *reinterpret_cast<const u32*>(ebf + (size_t)row * DIM + lane * 2);
    u32 pu = *reinterpret_cast<const u32*>(pbf + (size_t)label * DIM + lane * 2);
    float d = bf2f(eu & 0xFFFFu) * bf2f(pu & 0xFFFFu)
            + bf2f(eu >> 16)     * bf2f(pu >> 16);
    #pragma unroll
    for (int off = 1; off < 64; off <<= 1) d += __shfl_xor(d, off);

    if (lane == 0) {
        float e2 = esq[row], nm = nm2a[row];
        // exact pad-class correction: 96 zero-rows contributed exp2(fmaf(sqrt(e2+1),NS2,nm))
        // each (bitwise-same ops as gemm epilogue: fmaf(-2,0,ep)==ep, same FSQRT/fmaf/EXP2)
        float dp = FSQRT(e2 + 1.0f);
        float corr = 96.0f * EXP2(fmaf(dp, NS2, nm));
        float lse = -nm * (1.0f / LOG2E) + logf(S - corr);
        float sq = e2 + 1.0f - 2.0f * d;
        float pos = -SCALEF * FSQRT(fmaxf(sq, 0.0f));
        atomicAdd(out, (lse - pos) * cw[label] * (1.0f / BATCH));
    }
}

extern "C" void kernel_launch(void* const* d_in, const int* in_sizes, int n_in,
                              void* d_out, int out_size, void* d_ws, size_t ws_size,
                              hipStream_t stream) {
    const float* emb     = (const float*)d_in[0];
    const int*   labels  = (const int*)d_in[1];
    const float* cw      = (const float*)d_in[2];
    const float* proxies = (const float*)d_in[3];
    float* out = (float*)d_out;

    char* ws = (char*)d_ws;
    // layout (bytes):
    // pbf:  0          .. 25,624,576   (100096*128 bf16, incl. 96 zero pad rows)
    // ebf:  25,624,576 .. 26,148,864   (2048*128 bf16)
    // esq:  26,148,864 .. 26,157,056   (2048 f32)
    // nm2:  26,157,056 .. 26,165,248   (2048 f32)
    // ps:   26,165,248 .. 27,770,880   (196*2048 f32, [chunk][row])
    u16*   pbf  = (u16*)ws;
    u16*   ebf  = (u16*)(ws + 25624576);
    float* esq  = (float*)(ws + 26148864);
    float* nm2  = (float*)(ws + 26157056);
    float* ps   = (float*)(ws + 26165248);

    hipMemsetAsync(d_out, 0, sizeof(float), stream);
    prep_proxies_k<<<1564, 256, 0, stream>>>(proxies, pbf);
    prep_embed_k<<<512, 256, 0, stream>>>(emb, ebf, esq, nm2);
    gemm_lse_k<<<3136, 256, 0, stream>>>(pbf, ebf, esq, nm2, ps);
    combine_k<<<512, 256, 0, stream>>>(ps, ebf, pbf, esq, nm2, labels, cw, out);
}